// Round 9
// baseline (642.522 us; speedup 1.0000x reference)
//
#include <hip/hip_runtime.h>
#include <cmath>

struct K32 { float k[32]; };
struct K16 { float k[16]; };

#define THETA 10.0f

// ---------------- psp v5: division-free float4 staging, in-place LDS FIR ----------------
__global__ __launch_bounds__(256)
void psp_kernel(const float* __restrict__ in, float* __restrict__ out,
                int nrows, K32 pk) {
  __shared__ __align__(16) float lds[128 * 50];
  const int rowBase = blockIdx.x * 128;
  const int tid = threadIdx.x;
  const int vr = min(128, nrows - rowBase);   // always even here
  const int n4 = (vr * 50) >> 2;
  const float4* g4 = (const float4*)(in + (size_t)rowBase * 50);
  for (int i = tid; i < n4; i += 256) *(float4*)(&lds[4 * i]) = g4[i];
  __syncthreads();
  const int r = tid & 127;
  const int part = tid >> 7;
  const bool act = r < vr;
  float x[50];
  if (act) {
    if (part == 0) {
#pragma unroll
      for (int t = 0; t < 25; ++t) x[t] = lds[r * 50 + t];
    } else {
#pragma unroll
      for (int t = 0; t < 50; ++t) x[t] = lds[r * 50 + t];
    }
  }
  __syncthreads();
  if (act) {
    if (part == 0) {
#pragma unroll
      for (int t = 0; t < 25; ++t) {
        float a = 0.f;
#pragma unroll
        for (int k = 31; k >= 0; --k)          // x-index ascending (oldest first)
          if (t - k >= 0) a += x[t - k] * pk.k[k];
        lds[r * 50 + t] = a;
      }
    } else {
#pragma unroll
      for (int t = 25; t < 50; ++t) {
        float a = 0.f;
#pragma unroll
        for (int k = 31; k >= 0; --k)
          if (t - k >= 0) a += x[t - k] * pk.k[k];
        lds[r * 50 + t] = a;
      }
    }
  }
  __syncthreads();
  float4* o4 = (float4*)(out + (size_t)rowBase * 50);
  for (int i = tid; i < n4; i += 256) o4[i] = *(const float4*)(&lds[4 * i]);
}

// ---------------- fused conv (stride2,pad1) + spike [+ optional psp epilogue] ----------------
// R7-proven body; dims are template constants (addressing folds to immediates).
// PSP_OUT: spike thread keeps its row in registers and writes psp(spikes).
template <int CIN, int COUT, int KK, int WT, int HIN, int WIN, int HOUT, int WOUT,
          bool PSP_OUT>
__global__ __launch_bounds__(256)
void conv_spike_kernel(const float* __restrict__ x, const float* __restrict__ w,
                       float* __restrict__ s, K32 pk, K16 rk) {
  constexpr int XR = 2 * (WT - 1) + KK;
  constexpr int TW = 4 * WT;                 // wo span per block (4 waves)
  constexpr int GROUPS = (WOUT + TW - 1) / TW;
  __shared__ float lds[COUT * TW * 51];
  const int tid = threadIdx.x;
  const int wave = tid >> 6;
  const int lane = tid & 63;
  const int group = blockIdx.x % GROUPS;
  const int rest = blockIdx.x / GROUPS;
  const int ho = rest % HOUT;
  const int n = rest / HOUT;
  const int wo0 = group * TW + wave * WT;
  const int tt = lane < 50 ? lane : 49;

  float acc[COUT][WT] = {};
  for (int c = 0; c < CIN; ++c) {
#pragma unroll
    for (int kh = 0; kh < KK; ++kh) {
      const int hi = 2 * ho + kh - 1;
      if ((unsigned)hi >= (unsigned)HIN) continue;   // zero padding
      float xr[XR];
#pragma unroll
      for (int i = 0; i < XR; ++i) {
        const int wi = 2 * wo0 - 1 + i;
        xr[i] = ((unsigned)wi < (unsigned)WIN)
                    ? x[(((size_t)(n * CIN + c) * HIN + hi) * WIN + wi) * 50 + tt]
                    : 0.f;
      }
#pragma unroll
      for (int co = 0; co < COUT; ++co)
#pragma unroll
        for (int kw = 0; kw < KK; ++kw) {
          const float wv = w[((co * CIN + c) * KK + kh) * KK + kw];
#pragma unroll
          for (int wl = 0; wl < WT; ++wl)
            acc[co][wl] += xr[2 * wl + kw] * wv;
        }
    }
  }

  if (lane < 50) {
#pragma unroll
    for (int co = 0; co < COUT; ++co)
#pragma unroll
      for (int wl = 0; wl < WT; ++wl)
        lds[(co * TW + wave * WT + wl) * 51 + lane] = acc[co][wl];
  }
  __syncthreads();
  // spike along t, one thread per output row
  if (tid < COUT * TW) {
    const int wol = tid % TW;
    if (group * TW + wol < WOUT) {
      float buf[16];
      float y[PSP_OUT ? 50 : 1];
#pragma unroll
      for (int j = 0; j < 16; ++j) buf[j] = 0.f;
#pragma unroll
      for (int t = 0; t < 50; ++t) {
        float v = lds[tid * 51 + t] + buf[t & 15];
        buf[t & 15] = 0.f;
        float sp = 0.f;
        if (v >= THETA) {
          sp = 1.f;
#pragma unroll
          for (int j = 0; j < 16; ++j) buf[(t + 1 + j) & 15] += rk.k[j];
        }
        if (PSP_OUT) y[t] = sp; else lds[tid * 51 + t] = sp;
      }
      if (PSP_OUT) {
#pragma unroll
        for (int t = 0; t < 50; ++t) {
          float a = 0.f;
#pragma unroll
          for (int k = 31; k >= 0; --k)
            if (t - k >= 0) a += y[t - k] * pk.k[k];
          lds[tid * 51 + t] = a;
        }
      }
    }
  }
  __syncthreads();
  // store: float2 fast path when the group is full-width
  const int nv = min(TW, WOUT - group * TW);
  if (nv == TW) {
    constexpr int PER2 = TW * 25;
    for (int i2 = tid; i2 < COUT * PER2; i2 += 256) {
      const int co = i2 / PER2;
      const int r2 = i2 - co * PER2;
      const int wol = r2 / 25;
      const int j = r2 - wol * 25;
      float2 v;
      v.x = lds[(co * TW + wol) * 51 + 2 * j];
      v.y = lds[(co * TW + wol) * 51 + 2 * j + 1];
      *(float2*)(s + (((size_t)(n * COUT + co) * HOUT + ho) * WOUT + group * TW) * 50 + 2 * r2) = v;
    }
  } else {
    const int per = nv * 50;
    for (int i = tid; i < COUT * per; i += 256) {
      const int co = i / per;
      const int j = i - co * per;
      const int wol = j / 50;
      const int t = j - wol * 50;
      s[(((size_t)(n * COUT + co) * HOUT + ho) * WOUT + group * TW) * 50 + j] =
          lds[(co * TW + wol) * 51 + t];
    }
  }
}

// ---------------- pps v4: psp -> pool -> spike -> psp  (emits u = psp(pool spikes)) ----------------
__global__ __launch_bounds__(256)
void pps_kernel(const float* __restrict__ in, float* __restrict__ out,
                int Hin, int Win, int Hout, int Wout, int nseg,
                K32 pk, K16 rk) {
  __shared__ __align__(16) float lds[160 * 50];   // 32 KB
  const int tid = threadIdx.x;
  const int seg = blockIdx.x % nseg;
  const int rest = blockIdx.x / nseg;
  const int ho = rest % Hout;
  const int nc = rest / Hout;
  const int wbase = seg * 64;
  const int nw = min(64, 2 * Wout - wbase);   // 64 or 62 (even)
  const int nwo = nw >> 1;
  const int span = nw * 50;
  const float* b0 = in + ((size_t)(nc * Hin + 2 * ho) * Win + wbase) * 50;
  const float* b1 = b0 + (size_t)Win * 50;
  const int n2 = span >> 1;
  for (int i = tid; i < n2; i += 256) {
    *(float2*)(&lds[2 * i]) = *(const float2*)(b0 + 2 * i);
    *(float2*)(&lds[span + 2 * i]) = *(const float2*)(b1 + 2 * i);
  }
  __syncthreads();
  // FIR split across 2 threads/row, register snapshot -> barrier -> in-place
  const int r = tid & 127;
  const int part = tid >> 7;
  const bool act = r < 2 * nw;
  float x[50];
  if (act) {
    if (part == 0) {
#pragma unroll
      for (int t = 0; t < 25; ++t) x[t] = lds[r * 50 + t];
    } else {
#pragma unroll
      for (int t = 0; t < 50; ++t) x[t] = lds[r * 50 + t];
    }
  }
  __syncthreads();
  if (act) {
    if (part == 0) {
#pragma unroll
      for (int t = 0; t < 25; ++t) {
        float a = 0.f;
#pragma unroll
        for (int k = 31; k >= 0; --k)
          if (t - k >= 0) a += x[t - k] * pk.k[k];
        lds[r * 50 + t] = a;
      }
    } else {
#pragma unroll
      for (int t = 25; t < 50; ++t) {
        float a = 0.f;
#pragma unroll
        for (int k = 31; k >= 0; --k)
          if (t - k >= 0) a += x[t - k] * pk.k[k];
        lds[r * 50 + t] = a;
      }
    }
  }
  __syncthreads();
  // pool ((h0w0+h0w1)+h1w0)+h1w1 -> spike (kept in regs) -> psp -> rows [2nw, 2nw+nwo)
  if (tid < nwo) {
    float buf[16];
    float sp[50];
#pragma unroll
    for (int j = 0; j < 16; ++j) buf[j] = 0.f;
    const int r00 = (2 * tid) * 50, r01 = (2 * tid + 1) * 50;
    const int r10 = (nw + 2 * tid) * 50, r11 = (nw + 2 * tid + 1) * 50;
    const int ro = (2 * nw + tid) * 50;
#pragma unroll
    for (int t = 0; t < 50; ++t) {
      const float u0 = (((lds[r00 + t] + lds[r01 + t]) + lds[r10 + t]) + lds[r11 + t]) * 2.75f;
      float v = u0 + buf[t & 15];
      buf[t & 15] = 0.f;
      float spv = 0.f;
      if (v >= THETA) {
        spv = 1.f;
#pragma unroll
        for (int j = 0; j < 16; ++j) buf[(t + 1 + j) & 15] += rk.k[j];
      }
      sp[t] = spv;
    }
#pragma unroll
    for (int t = 0; t < 50; ++t) {
      float a = 0.f;
#pragma unroll
      for (int k = 31; k >= 0; --k)
        if (t - k >= 0) a += sp[t - k] * pk.k[k];
      lds[ro + t] = a;
    }
  }
  __syncthreads();
  float* ob = out + ((size_t)(nc * Hout + ho) * Wout + seg * 32) * 50;
  const int base = 2 * nw * 50;
  for (int i = tid; i < nwo * 25; i += 256)
    *(float2*)(ob + 2 * i) = *(const float2*)(&lds[base + 2 * i]);
}

// ---------------- fused fc + final spike: wave per (n,o), lane = t ----------------
__global__ __launch_bounds__(512)
void fc_spike_kernel(const float* __restrict__ w, const float* __restrict__ u,
                     float* __restrict__ out, K16 rk) {
  __shared__ float lds[8 * 51];
  const int tid = threadIdx.x;
  const int wave = tid >> 6, lane = tid & 63;
  const int o = wave & 1, n = wave >> 1;
  const int tt = lane < 50 ? lane : 49;
  const float* wrow = w + (size_t)o * 2048;
  const float* ub = u + (size_t)n * 2048 * 50;
  float acc = 0.f;
#pragma unroll 32
  for (int i = 0; i < 2048; ++i) acc += wrow[i] * ub[(size_t)i * 50 + tt];
  if (lane < 50) lds[wave * 51 + lane] = acc;
  __syncthreads();
  if (tid < 8) {
    float buf[16];
#pragma unroll
    for (int j = 0; j < 16; ++j) buf[j] = 0.f;
#pragma unroll
    for (int t = 0; t < 50; ++t) {
      float v = lds[tid * 51 + t] + buf[t & 15];
      buf[t & 15] = 0.f;
      float sp = 0.f;
      if (v >= THETA) {
        sp = 1.f;
#pragma unroll
        for (int j = 0; j < 16; ++j) buf[(t + 1 + j) & 15] += rk.k[j];
      }
      out[tid * 50 + t] = sp;
    }
  }
}

extern "C" void kernel_launch(void* const* d_in, const int* in_sizes, int n_in,
                              void* d_out, int out_size, void* d_ws, size_t ws_size,
                              hipStream_t stream) {
  const float* xin = (const float*)d_in[0];  // [4,2,256,256,50]
  const float* w1  = (const float*)d_in[1];  // [8,2,5,5]
  const float* w2  = (const float*)d_in[2];  // [16,8,3,3]
  const float* w3  = (const float*)d_in[3];  // [32,16,3,3]
  const float* wfc = (const float*)d_in[4];  // [2,32,8,8]
  float* out = (float*)d_out;                // [4,2,1,1,50]

  float* R0 = (float*)d_ws;                  // 26,214,400 floats
  float* R1 = R0 + 26214400;

  K32 pk;
  for (int k = 0; k < 32; ++k)
    pk.k[k] = (float)(((double)k / 10.0) * exp(1.0 - (double)k / 10.0));
  K16 rk;
  for (int j = 0; j < 16; ++j) {
    const double tr = (double)(j + 1);
    rk.k[j] = (float)(-2.0 * 10.0 * tr * exp(1.0 - tr));
  }

  // 1. psp1: xin -> R0 = u1
  psp_kernel<<<4096, 256, 0, stream>>>(xin, R0, 524288, pk);
  // 2. conv1+spike1: R0 -> R1 = s1 [4,8,127,127,50]
  conv_spike_kernel<2, 8, 5, 4, 256, 256, 127, 127, false>
      <<<4 * 127 * 8, 256, 0, stream>>>(R0, w1, R1, pk, rk);
  // 3. psp+pool+spike+psp: R1 -> R0 = u3 = psp(s2) [4,8,63,63,50]
  pps_kernel<<<4 * 8 * 63 * 2, 256, 0, stream>>>(R1, R0, 127, 127, 63, 63, 2, pk, rk);
  // 4. conv2+spike3: R0 -> R1 = s3 [4,16,32,32,50]
  conv_spike_kernel<8, 16, 3, 2, 63, 63, 32, 32, false>
      <<<4 * 32 * 4, 256, 0, stream>>>(R0, w2, R1, pk, rk);
  // 5. psp+pool+spike+psp: R1 -> R0 = u5 = psp(s4) [4,16,16,16,50]
  pps_kernel<<<4 * 16 * 16, 256, 0, stream>>>(R1, R0, 32, 32, 16, 16, 1, pk, rk);
  // 6. conv3+spike5+psp6: R0 -> R1 = u6 = psp(s5) [4,32,8,8,50]
  conv_spike_kernel<16, 32, 3, 1, 16, 16, 8, 8, true>
      <<<4 * 8 * 2, 256, 0, stream>>>(R0, w3, R1, pk, rk);
  // 7. fc + final spike -> out
  fc_spike_kernel<<<1, 512, 0, stream>>>(wfc, R1, out, rk);
}

// Round 10
// 539.998 us; speedup vs baseline: 1.1899x; 1.1899x over previous
//
#include <hip/hip_runtime.h>
#include <cmath>

struct K32 { float k[32]; };
struct K16 { float k[16]; };

#define THETA 10.0f

// ---------------- psp v5: division-free float4 staging, in-place LDS FIR ----------------
__global__ __launch_bounds__(256)
void psp_kernel(const float* __restrict__ in, float* __restrict__ out,
                int nrows, K32 pk) {
  __shared__ __align__(16) float lds[128 * 50];
  const int rowBase = blockIdx.x * 128;
  const int tid = threadIdx.x;
  const int vr = min(128, nrows - rowBase);   // always even here
  const int n4 = (vr * 50) >> 2;
  const float4* g4 = (const float4*)(in + (size_t)rowBase * 50);
  for (int i = tid; i < n4; i += 256) *(float4*)(&lds[4 * i]) = g4[i];
  __syncthreads();
  const int r = tid & 127;
  const int part = tid >> 7;
  const bool act = r < vr;
  float x[50];
  if (act) {
    if (part == 0) {
#pragma unroll
      for (int t = 0; t < 25; ++t) x[t] = lds[r * 50 + t];
    } else {
#pragma unroll
      for (int t = 0; t < 50; ++t) x[t] = lds[r * 50 + t];
    }
  }
  __syncthreads();
  if (act) {
    if (part == 0) {
#pragma unroll
      for (int t = 0; t < 25; ++t) {
        float a = 0.f;
#pragma unroll
        for (int k = 31; k >= 0; --k)          // x-index ascending (oldest first)
          if (t - k >= 0) a += x[t - k] * pk.k[k];
        lds[r * 50 + t] = a;
      }
    } else {
#pragma unroll
      for (int t = 25; t < 50; ++t) {
        float a = 0.f;
#pragma unroll
        for (int k = 31; k >= 0; --k)
          if (t - k >= 0) a += x[t - k] * pk.k[k];
        lds[r * 50 + t] = a;
      }
    }
  }
  __syncthreads();
  float4* o4 = (float4*)(out + (size_t)rowBase * 50);
  for (int i = tid; i < n4; i += 256) o4[i] = *(const float4*)(&lds[4 * i]);
}

// ---------------- fused conv (stride2,pad1) + spike — R7/R8-proven body ----------------
template <int CIN, int COUT, int KK, int WT>
__global__ __launch_bounds__(256)
void conv_spike_kernel(const float* __restrict__ x, const float* __restrict__ w,
                       float* __restrict__ s, int N, int Hin, int Win,
                       int Hout, int Wout, K16 rk) {
  constexpr int XR = 2 * (WT - 1) + KK;
  constexpr int TW = 4 * WT;                 // wo span per block (4 waves)
  __shared__ float lds[COUT * TW * 51];
  const int tid = threadIdx.x;
  const int wave = tid >> 6;
  const int lane = tid & 63;
  const int groups = (Wout + TW - 1) / TW;
  const int group = blockIdx.x % groups;
  const int rest = blockIdx.x / groups;
  const int ho = rest % Hout;
  const int n = rest / Hout;
  const int wo0 = group * TW + wave * WT;
  const int tt = lane < 50 ? lane : 49;

  float acc[COUT][WT] = {};
  for (int c = 0; c < CIN; ++c) {
#pragma unroll
    for (int kh = 0; kh < KK; ++kh) {
      const int hi = 2 * ho + kh - 1;
      if ((unsigned)hi >= (unsigned)Hin) continue;   // zero padding
      float xr[XR];
#pragma unroll
      for (int i = 0; i < XR; ++i) {
        const int wi = 2 * wo0 - 1 + i;
        xr[i] = ((unsigned)wi < (unsigned)Win)
                    ? x[(((size_t)(n * CIN + c) * Hin + hi) * Win + wi) * 50 + tt]
                    : 0.f;
      }
#pragma unroll
      for (int co = 0; co < COUT; ++co)
#pragma unroll
        for (int kw = 0; kw < KK; ++kw) {
          const float wv = w[((co * CIN + c) * KK + kh) * KK + kw];
#pragma unroll
          for (int wl = 0; wl < WT; ++wl)
            acc[co][wl] += xr[2 * wl + kw] * wv;
        }
    }
  }

  if (lane < 50) {
#pragma unroll
    for (int co = 0; co < COUT; ++co)
#pragma unroll
      for (int wl = 0; wl < WT; ++wl)
        lds[(co * TW + wave * WT + wl) * 51 + lane] = acc[co][wl];
  }
  __syncthreads();
  // spike along t, one thread per output row, in place
  if (tid < COUT * TW) {
    const int wol = tid % TW;
    if (group * TW + wol < Wout) {
      float buf[16];
#pragma unroll
      for (int j = 0; j < 16; ++j) buf[j] = 0.f;
#pragma unroll
      for (int t = 0; t < 50; ++t) {
        float v = lds[tid * 51 + t] + buf[t & 15];
        buf[t & 15] = 0.f;
        float sp = 0.f;
        if (v >= THETA) {
          sp = 1.f;
#pragma unroll
          for (int j = 0; j < 16; ++j) buf[(t + 1 + j) & 15] += rk.k[j];
        }
        lds[tid * 51 + t] = sp;
      }
    }
  }
  __syncthreads();
  // store: float2 fast path when the group is full-width
  const int nv = min(TW, Wout - group * TW);
  if (nv == TW) {
    constexpr int PER2 = TW * 25;
    for (int i2 = tid; i2 < COUT * PER2; i2 += 256) {
      const int co = i2 / PER2;
      const int r2 = i2 - co * PER2;
      const int wol = r2 / 25;
      const int j = r2 - wol * 25;
      float2 v;
      v.x = lds[(co * TW + wol) * 51 + 2 * j];
      v.y = lds[(co * TW + wol) * 51 + 2 * j + 1];
      *(float2*)(s + (((size_t)(n * COUT + co) * Hout + ho) * Wout + group * TW) * 50 + 2 * r2) = v;
    }
  } else {
    const int per = nv * 50;
    for (int i = tid; i < COUT * per; i += 256) {
      const int co = i / per;
      const int j = i - co * per;
      const int wol = j / 50;
      const int t = j - wol * 50;
      s[(((size_t)(n * COUT + co) * Hout + ho) * Wout + group * TW) * 50 + j] =
          lds[(co * TW + wol) * 51 + t];
    }
  }
}

// ---------------- pps v5: 128-thread blocks, 32-col segments, 16 KB LDS ----------------
// LDS rows stride 50: [0,nw) = h0 span, [nw,2nw) = h1 span (contiguous copies
// of global), spikes to [2nw, 2nw+nwo). FIR 2 threads/row; pool+spike 1/wo.
__global__ __launch_bounds__(128)
void pps_kernel(const float* __restrict__ in, float* __restrict__ out,
                int Hin, int Win, int Hout, int Wout, int nseg,
                K32 pk, K16 rk) {
  __shared__ __align__(16) float lds[80 * 50];   // 16 KB
  const int tid = threadIdx.x;
  const int seg = blockIdx.x % nseg;
  const int rest = blockIdx.x / nseg;
  const int ho = rest % Hout;
  const int nc = rest / Hout;
  const int wbase = seg * 32;                 // input col base
  const int nw = min(32, 2 * Wout - wbase);   // even (30 or 32)
  const int nwo = nw >> 1;
  const int span = nw * 50;
  const float* b0 = in + ((size_t)(nc * Hin + 2 * ho) * Win + wbase) * 50;
  const float* b1 = b0 + (size_t)Win * 50;
  const int n2 = span >> 1;
  for (int i = tid; i < n2; i += 128) {
    *(float2*)(&lds[2 * i]) = *(const float2*)(b0 + 2 * i);
    *(float2*)(&lds[span + 2 * i]) = *(const float2*)(b1 + 2 * i);
  }
  __syncthreads();
  // FIR split across 2 threads/row, register snapshot -> barrier -> in-place
  const int r = tid & 63;
  const int part = tid >> 6;
  const bool act = r < 2 * nw;
  float x[50];
  if (act) {
    if (part == 0) {
#pragma unroll
      for (int t = 0; t < 25; ++t) x[t] = lds[r * 50 + t];
    } else {
#pragma unroll
      for (int t = 0; t < 50; ++t) x[t] = lds[r * 50 + t];
    }
  }
  __syncthreads();
  if (act) {
    if (part == 0) {
#pragma unroll
      for (int t = 0; t < 25; ++t) {
        float a = 0.f;
#pragma unroll
        for (int k = 31; k >= 0; --k)
          if (t - k >= 0) a += x[t - k] * pk.k[k];
        lds[r * 50 + t] = a;
      }
    } else {
#pragma unroll
      for (int t = 25; t < 50; ++t) {
        float a = 0.f;
#pragma unroll
        for (int k = 31; k >= 0; --k)
          if (t - k >= 0) a += x[t - k] * pk.k[k];
        lds[r * 50 + t] = a;
      }
    }
  }
  __syncthreads();
  // pool ((h0w0+h0w1)+h1w0)+h1w1 then spike -> rows [2nw, 2nw+nwo)
  if (tid < nwo) {
    float buf[16];
#pragma unroll
    for (int j = 0; j < 16; ++j) buf[j] = 0.f;
    const int r00 = (2 * tid) * 50, r01 = (2 * tid + 1) * 50;
    const int r10 = (nw + 2 * tid) * 50, r11 = (nw + 2 * tid + 1) * 50;
    const int ro = (2 * nw + tid) * 50;
#pragma unroll
    for (int t = 0; t < 50; ++t) {
      const float u0 = (((lds[r00 + t] + lds[r01 + t]) + lds[r10 + t]) + lds[r11 + t]) * 2.75f;
      float v = u0 + buf[t & 15];
      buf[t & 15] = 0.f;
      float sp = 0.f;
      if (v >= THETA) {
        sp = 1.f;
#pragma unroll
        for (int j = 0; j < 16; ++j) buf[(t + 1 + j) & 15] += rk.k[j];
      }
      lds[ro + t] = sp;
    }
  }
  __syncthreads();
  float* ob = out + ((size_t)(nc * Hout + ho) * Wout + seg * 16) * 50;
  const int base = 2 * nw * 50;
  for (int i = tid; i < nwo * 25; i += 128)
    *(float2*)(ob + 2 * i) = *(const float2*)(&lds[base + 2 * i]);
}

// ---------------- fused fc + final spike: wave per (n,o), lane = t ----------------
__global__ __launch_bounds__(512)
void fc_spike_kernel(const float* __restrict__ w, const float* __restrict__ u,
                     float* __restrict__ out, K16 rk) {
  __shared__ float lds[8 * 51];
  const int tid = threadIdx.x;
  const int wave = tid >> 6, lane = tid & 63;
  const int o = wave & 1, n = wave >> 1;
  const int tt = lane < 50 ? lane : 49;
  const float* wrow = w + (size_t)o * 2048;
  const float* ub = u + (size_t)n * 2048 * 50;
  float acc = 0.f;
#pragma unroll 32
  for (int i = 0; i < 2048; ++i) acc += wrow[i] * ub[(size_t)i * 50 + tt];
  if (lane < 50) lds[wave * 51 + lane] = acc;
  __syncthreads();
  if (tid < 8) {
    float buf[16];
#pragma unroll
    for (int j = 0; j < 16; ++j) buf[j] = 0.f;
#pragma unroll
    for (int t = 0; t < 50; ++t) {
      float v = lds[tid * 51 + t] + buf[t & 15];
      buf[t & 15] = 0.f;
      float sp = 0.f;
      if (v >= THETA) {
        sp = 1.f;
#pragma unroll
        for (int j = 0; j < 16; ++j) buf[(t + 1 + j) & 15] += rk.k[j];
      }
      out[tid * 50 + t] = sp;
    }
  }
}

extern "C" void kernel_launch(void* const* d_in, const int* in_sizes, int n_in,
                              void* d_out, int out_size, void* d_ws, size_t ws_size,
                              hipStream_t stream) {
  const float* xin = (const float*)d_in[0];  // [4,2,256,256,50]
  const float* w1  = (const float*)d_in[1];  // [8,2,5,5]
  const float* w2  = (const float*)d_in[2];  // [16,8,3,3]
  const float* w3  = (const float*)d_in[3];  // [32,16,3,3]
  const float* wfc = (const float*)d_in[4];  // [2,32,8,8]
  float* out = (float*)d_out;                // [4,2,1,1,50]

  float* R0 = (float*)d_ws;                  // 26,214,400 floats
  float* R1 = R0 + 26214400;

  K32 pk;
  for (int k = 0; k < 32; ++k)
    pk.k[k] = (float)(((double)k / 10.0) * exp(1.0 - (double)k / 10.0));
  K16 rk;
  for (int j = 0; j < 16; ++j) {
    const double tr = (double)(j + 1);
    rk.k[j] = (float)(-2.0 * 10.0 * tr * exp(1.0 - tr));
  }

  // 1. psp1: xin -> R0 = u1 (524288 rows)
  psp_kernel<<<4096, 256, 0, stream>>>(xin, R0, 524288, pk);
  // 2. conv1+spike1: R0 -> R1 = s1 [4,8,127,127,50]
  conv_spike_kernel<2, 8, 5, 4><<<4 * 127 * 8, 256, 0, stream>>>(R0, w1, R1, 4, 256, 256, 127, 127, rk);
  // 3. psp+pool+spike: R1 -> R0 = s2 [4,8,63,63,50]; nseg=4, 128-thread blocks
  pps_kernel<<<4 * 8 * 63 * 4, 128, 0, stream>>>(R1, R0, 127, 127, 63, 63, 4, pk, rk);
  // 4. psp3: R0 -> R1 (127008 rows)
  psp_kernel<<<993, 256, 0, stream>>>(R0, R1, 127008, pk);
  // 5. conv2+spike3: R1 -> R0 = s3 [4,16,32,32,50]; WT=1 -> 1024 blocks
  conv_spike_kernel<8, 16, 3, 1><<<4 * 32 * 8, 256, 0, stream>>>(R1, w2, R0, 4, 63, 63, 32, 32, rk);
  // 6. psp+pool+spike: R0 -> R1 = s4 [4,16,16,16,50]; nseg=1
  pps_kernel<<<4 * 16 * 16, 128, 0, stream>>>(R0, R1, 32, 32, 16, 16, 1, pk, rk);
  // 7. psp5: R1 -> R0 (16384 rows)
  psp_kernel<<<128, 256, 0, stream>>>(R1, R0, 16384, pk);
  // 8. conv3+spike5: R0 -> R1 = s5 [4,32,8,8,50]
  conv_spike_kernel<16, 32, 3, 1><<<4 * 8 * 2, 256, 0, stream>>>(R0, w3, R1, 4, 16, 16, 8, 8, rk);
  // 9. psp6: R1 -> R0 (8192 rows)
  psp_kernel<<<64, 256, 0, stream>>>(R1, R0, 8192, pk);
  // 10. fc + final spike -> out
  fc_spike_kernel<<<1, 512, 0, stream>>>(wfc, R0, out, rk);
}

// Round 11
// 531.312 us; speedup vs baseline: 1.2093x; 1.0163x over previous
//
#include <hip/hip_runtime.h>
#include <cmath>

struct K32 { float k[32]; };
struct K16 { float k[16]; };

#define THETA 10.0f

// ---------------- psp v5: division-free float4 staging, in-place LDS FIR ----------------
__global__ __launch_bounds__(256)
void psp_kernel(const float* __restrict__ in, float* __restrict__ out,
                int nrows, K32 pk) {
  __shared__ __align__(16) float lds[128 * 50];
  const int rowBase = blockIdx.x * 128;
  const int tid = threadIdx.x;
  const int vr = min(128, nrows - rowBase);   // always even here
  const int n4 = (vr * 50) >> 2;
  const float4* g4 = (const float4*)(in + (size_t)rowBase * 50);
  for (int i = tid; i < n4; i += 256) *(float4*)(&lds[4 * i]) = g4[i];
  __syncthreads();
  const int r = tid & 127;
  const int part = tid >> 7;
  const bool act = r < vr;
  float x[50];
  if (act) {
    if (part == 0) {
#pragma unroll
      for (int t = 0; t < 25; ++t) x[t] = lds[r * 50 + t];
    } else {
#pragma unroll
      for (int t = 0; t < 50; ++t) x[t] = lds[r * 50 + t];
    }
  }
  __syncthreads();
  if (act) {
    if (part == 0) {
#pragma unroll
      for (int t = 0; t < 25; ++t) {
        float a = 0.f;
#pragma unroll
        for (int k = 31; k >= 0; --k)          // x-index ascending (oldest first)
          if (t - k >= 0) a += x[t - k] * pk.k[k];
        lds[r * 50 + t] = a;
      }
    } else {
#pragma unroll
      for (int t = 25; t < 50; ++t) {
        float a = 0.f;
#pragma unroll
        for (int k = 31; k >= 0; --k)
          if (t - k >= 0) a += x[t - k] * pk.k[k];
        lds[r * 50 + t] = a;
      }
    }
  }
  __syncthreads();
  float4* o4 = (float4*)(out + (size_t)rowBase * 50);
  for (int i = tid; i < n4; i += 256) o4[i] = *(const float4*)(&lds[4 * i]);
}

// ---------------- fused conv (stride2,pad1) + spike, direct register store ----------------
// wave=(n,ho,wo-tile), lane=t. Checked loads (R7-proven). After acc->LDS
// transpose + 1 barrier, each spike thread owns a contiguous 200B output row
// and stores float2 pairs directly — no 2nd barrier, no store loop.
template <int CIN, int COUT, int KK, int WT, int HIN, int WIN, int HOUT, int WOUT>
__global__ __launch_bounds__(256)
void conv_spike_kernel(const float* __restrict__ x, const float* __restrict__ w,
                       float* __restrict__ s, K16 rk) {
  constexpr int XR = 2 * (WT - 1) + KK;
  constexpr int TW = 4 * WT;                 // wo span per block (4 waves)
  constexpr int GROUPS = (WOUT + TW - 1) / TW;
  __shared__ float lds[COUT * TW * 51];
  const int tid = threadIdx.x;
  const int wave = tid >> 6;
  const int lane = tid & 63;
  const int group = blockIdx.x % GROUPS;
  const int rest = blockIdx.x / GROUPS;
  const int ho = rest % HOUT;
  const int n = rest / HOUT;
  const int wo0 = group * TW + wave * WT;
  const int tt = lane < 50 ? lane : 49;

  float acc[COUT][WT] = {};
  for (int c = 0; c < CIN; ++c) {
#pragma unroll
    for (int kh = 0; kh < KK; ++kh) {
      const int hi = 2 * ho + kh - 1;
      if ((unsigned)hi >= (unsigned)HIN) continue;   // zero padding
      float xr[XR];
#pragma unroll
      for (int i = 0; i < XR; ++i) {
        const int wi = 2 * wo0 - 1 + i;
        xr[i] = ((unsigned)wi < (unsigned)WIN)
                    ? x[(((size_t)(n * CIN + c) * HIN + hi) * WIN + wi) * 50 + tt]
                    : 0.f;
      }
#pragma unroll
      for (int co = 0; co < COUT; ++co)
#pragma unroll
        for (int kw = 0; kw < KK; ++kw) {
          const float wv = w[((co * CIN + c) * KK + kh) * KK + kw];
#pragma unroll
          for (int wl = 0; wl < WT; ++wl)
            acc[co][wl] += xr[2 * wl + kw] * wv;
        }
    }
  }

  if (lane < 50) {
#pragma unroll
    for (int co = 0; co < COUT; ++co)
#pragma unroll
      for (int wl = 0; wl < WT; ++wl)
        lds[(co * TW + wave * WT + wl) * 51 + lane] = acc[co][wl];
  }
  __syncthreads();
  // spike along t, one thread per output row, direct float2 store from regs
  if (tid < COUT * TW) {
    const int co = tid / TW;
    const int wol = tid - co * TW;
    const int wo = group * TW + wol;
    if (wo < WOUT) {
      float* orow = s + (((size_t)(n * COUT + co) * HOUT + ho) * WOUT + wo) * 50;
      float buf[16];
#pragma unroll
      for (int j = 0; j < 16; ++j) buf[j] = 0.f;
      float prev = 0.f;
#pragma unroll
      for (int t = 0; t < 50; ++t) {
        float v = lds[tid * 51 + t] + buf[t & 15];
        buf[t & 15] = 0.f;
        float sp = 0.f;
        if (v >= THETA) {
          sp = 1.f;
#pragma unroll
          for (int j = 0; j < 16; ++j) buf[(t + 1 + j) & 15] += rk.k[j];
        }
        if (t & 1) *(float2*)(orow + t - 1) = make_float2(prev, sp);
        else prev = sp;
      }
    }
  }
}

// ---------------- pps v5: 128-thread blocks, 32-col segments, 16 KB LDS ----------------
__global__ __launch_bounds__(128)
void pps_kernel(const float* __restrict__ in, float* __restrict__ out,
                int Hin, int Win, int Hout, int Wout, int nseg,
                K32 pk, K16 rk) {
  __shared__ __align__(16) float lds[80 * 50];   // 16 KB
  const int tid = threadIdx.x;
  const int seg = blockIdx.x % nseg;
  const int rest = blockIdx.x / nseg;
  const int ho = rest % Hout;
  const int nc = rest / Hout;
  const int wbase = seg * 32;                 // input col base
  const int nw = min(32, 2 * Wout - wbase);   // even (30 or 32)
  const int nwo = nw >> 1;
  const int span = nw * 50;
  const float* b0 = in + ((size_t)(nc * Hin + 2 * ho) * Win + wbase) * 50;
  const float* b1 = b0 + (size_t)Win * 50;
  const int n2 = span >> 1;
  for (int i = tid; i < n2; i += 128) {
    *(float2*)(&lds[2 * i]) = *(const float2*)(b0 + 2 * i);
    *(float2*)(&lds[span + 2 * i]) = *(const float2*)(b1 + 2 * i);
  }
  __syncthreads();
  // FIR split across 2 threads/row, register snapshot -> barrier -> in-place
  const int r = tid & 63;
  const int part = tid >> 6;
  const bool act = r < 2 * nw;
  float x[50];
  if (act) {
    if (part == 0) {
#pragma unroll
      for (int t = 0; t < 25; ++t) x[t] = lds[r * 50 + t];
    } else {
#pragma unroll
      for (int t = 0; t < 50; ++t) x[t] = lds[r * 50 + t];
    }
  }
  __syncthreads();
  if (act) {
    if (part == 0) {
#pragma unroll
      for (int t = 0; t < 25; ++t) {
        float a = 0.f;
#pragma unroll
        for (int k = 31; k >= 0; --k)
          if (t - k >= 0) a += x[t - k] * pk.k[k];
        lds[r * 50 + t] = a;
      }
    } else {
#pragma unroll
      for (int t = 25; t < 50; ++t) {
        float a = 0.f;
#pragma unroll
        for (int k = 31; k >= 0; --k)
          if (t - k >= 0) a += x[t - k] * pk.k[k];
        lds[r * 50 + t] = a;
      }
    }
  }
  __syncthreads();
  // pool ((h0w0+h0w1)+h1w0)+h1w1 then spike -> rows [2nw, 2nw+nwo)
  if (tid < nwo) {
    float buf[16];
#pragma unroll
    for (int j = 0; j < 16; ++j) buf[j] = 0.f;
    const int r00 = (2 * tid) * 50, r01 = (2 * tid + 1) * 50;
    const int r10 = (nw + 2 * tid) * 50, r11 = (nw + 2 * tid + 1) * 50;
    const int ro = (2 * nw + tid) * 50;
#pragma unroll
    for (int t = 0; t < 50; ++t) {
      const float u0 = (((lds[r00 + t] + lds[r01 + t]) + lds[r10 + t]) + lds[r11 + t]) * 2.75f;
      float v = u0 + buf[t & 15];
      buf[t & 15] = 0.f;
      float sp = 0.f;
      if (v >= THETA) {
        sp = 1.f;
#pragma unroll
        for (int j = 0; j < 16; ++j) buf[(t + 1 + j) & 15] += rk.k[j];
      }
      lds[ro + t] = sp;
    }
  }
  __syncthreads();
  float* ob = out + ((size_t)(nc * Hout + ho) * Wout + seg * 16) * 50;
  const int base = 2 * nw * 50;
  for (int i = tid; i < nwo * 25; i += 128)
    *(float2*)(ob + 2 * i) = *(const float2*)(&lds[base + 2 * i]);
}

// ---------------- fused fc + final spike: wave per (n,o), lane = t ----------------
__global__ __launch_bounds__(512)
void fc_spike_kernel(const float* __restrict__ w, const float* __restrict__ u,
                     float* __restrict__ out, K16 rk) {
  __shared__ float lds[8 * 51];
  const int tid = threadIdx.x;
  const int wave = tid >> 6, lane = tid & 63;
  const int o = wave & 1, n = wave >> 1;
  const int tt = lane < 50 ? lane : 49;
  const float* wrow = w + (size_t)o * 2048;
  const float* ub = u + (size_t)n * 2048 * 50;
  float acc = 0.f;
#pragma unroll 32
  for (int i = 0; i < 2048; ++i) acc += wrow[i] * ub[(size_t)i * 50 + tt];
  if (lane < 50) lds[wave * 51 + lane] = acc;
  __syncthreads();
  if (tid < 8) {
    float buf[16];
#pragma unroll
    for (int j = 0; j < 16; ++j) buf[j] = 0.f;
#pragma unroll
    for (int t = 0; t < 50; ++t) {
      float v = lds[tid * 51 + t] + buf[t & 15];
      buf[t & 15] = 0.f;
      float sp = 0.f;
      if (v >= THETA) {
        sp = 1.f;
#pragma unroll
        for (int j = 0; j < 16; ++j) buf[(t + 1 + j) & 15] += rk.k[j];
      }
      out[tid * 50 + t] = sp;
    }
  }
}

extern "C" void kernel_launch(void* const* d_in, const int* in_sizes, int n_in,
                              void* d_out, int out_size, void* d_ws, size_t ws_size,
                              hipStream_t stream) {
  const float* xin = (const float*)d_in[0];  // [4,2,256,256,50]
  const float* w1  = (const float*)d_in[1];  // [8,2,5,5]
  const float* w2  = (const float*)d_in[2];  // [16,8,3,3]
  const float* w3  = (const float*)d_in[3];  // [32,16,3,3]
  const float* wfc = (const float*)d_in[4];  // [2,32,8,8]
  float* out = (float*)d_out;                // [4,2,1,1,50]

  float* R0 = (float*)d_ws;                  // 26,214,400 floats
  float* R1 = R0 + 26214400;

  K32 pk;
  for (int k = 0; k < 32; ++k)
    pk.k[k] = (float)(((double)k / 10.0) * exp(1.0 - (double)k / 10.0));
  K16 rk;
  for (int j = 0; j < 16; ++j) {
    const double tr = (double)(j + 1);
    rk.k[j] = (float)(-2.0 * 10.0 * tr * exp(1.0 - tr));
  }

  // 1. psp1: xin -> R0 = u1 (524288 rows)
  psp_kernel<<<4096, 256, 0, stream>>>(xin, R0, 524288, pk);
  // 2. conv1+spike1: R0 -> R1 = s1 [4,8,127,127,50]; GROUPS=8
  conv_spike_kernel<2, 8, 5, 4, 256, 256, 127, 127>
      <<<4 * 127 * 8, 256, 0, stream>>>(R0, w1, R1, rk);
  // 3. psp+pool+spike: R1 -> R0 = s2 [4,8,63,63,50]; nseg=4, 128-thread blocks
  pps_kernel<<<4 * 8 * 63 * 4, 128, 0, stream>>>(R1, R0, 127, 127, 63, 63, 4, pk, rk);
  // 4. psp3: R0 -> R1 (127008 rows)
  psp_kernel<<<993, 256, 0, stream>>>(R0, R1, 127008, pk);
  // 5. conv2+spike3: R1 -> R0 = s3 [4,16,32,32,50]; WT=1 -> GROUPS=8, 1024 blocks
  conv_spike_kernel<8, 16, 3, 1, 63, 63, 32, 32>
      <<<4 * 32 * 8, 256, 0, stream>>>(R1, w2, R0, rk);
  // 6. psp+pool+spike: R0 -> R1 = s4 [4,16,16,16,50]; nseg=1
  pps_kernel<<<4 * 16 * 16, 128, 0, stream>>>(R0, R1, 32, 32, 16, 16, 1, pk, rk);
  // 7. psp5: R1 -> R0 (16384 rows)
  psp_kernel<<<128, 256, 0, stream>>>(R1, R0, 16384, pk);
  // 8. conv3+spike5: R0 -> R1 = s5 [4,32,8,8,50]; GROUPS=2, 64 blocks
  conv_spike_kernel<16, 32, 3, 1, 16, 16, 8, 8>
      <<<4 * 8 * 2, 256, 0, stream>>>(R0, w3, R1, rk);
  // 9. psp6: R1 -> R0 (8192 rows)
  psp_kernel<<<64, 256, 0, stream>>>(R1, R0, 8192, pk);
  // 10. fc + final spike -> out
  fc_spike_kernel<<<1, 512, 0, stream>>>(wfc, R0, out, rk);
}